// Round 9
// baseline (383.666 us; speedup 1.0000x reference)
//
#include <hip/hip_runtime.h>
#include <hip/hip_bf16.h>

// Problem constants (match reference setup_inputs)
#define NN 30000      // nodes
#define NE 600000     // edges
#define DD 128        // feature dim
#define RR 7          // relations
#define GG 16         // graphs
#define LL 3          // layers

#define NB64 ((NN + 63) / 64)   // 469 buckets of 64 nodes

// fused-prologue work partition
#define NPK (LL * 8 * 128 * 32)   // weight pack: thread = 4 k-pos -> ushort4
#define NCV (NN * 32)             // x->bf16: thread = 4 positions -> ushort4

typedef short bf16x8 __attribute__((ext_vector_type(8)));  // 8 bf16 = 4 VGPRs
typedef float f32x4  __attribute__((ext_vector_type(4)));
typedef float f32x2  __attribute__((ext_vector_type(2)));

// Feature-position permutation (per 64-col span): pos = (c&15)*4 + (c>>4),
// inverse c = (p&3)*16 + (p>>2). h buffers and upd live in position space;
// the GEMM epilogue's store pattern realizes P, so packed weights are indexed
// by LOGICAL output column; only the k dim is position-permuted.
// Numerics: h bf16, weights bf16 (NO weight quantization — round-8's
// systematic-error lesson), upd fp8 (random per-node error, validated shape).

// ---- helpers ---------------------------------------------------------------
__device__ __forceinline__ unsigned short f2bf(float f) {
    unsigned u = __float_as_uint(f);
    unsigned r = (u + 0x7fffu + ((u >> 16) & 1u)) >> 16;   // round-nearest-even
    return (unsigned short)r;
}
__device__ __forceinline__ ushort2 pk2bf(float a, float b) {
    __hip_bfloat162 t = __float22bfloat162_rn(make_float2(a, b));
    return *(ushort2*)&t;
}
__device__ __forceinline__ void gl_lds16(const void* g, void* l) {
    __builtin_amdgcn_global_load_lds(
        (const __attribute__((address_space(1))) void*)g,
        (__attribute__((address_space(3))) void*)l, 16, 0, 0);
}

// ---------------------------------------------------------------------------
// Fused prologue: weight pack (bf16) + x->bf16 (position space) + zeroing.
// Bw16 layout: [l][ch][n][k_pos] bf16; ch0 = Wl, ch r+1 = Wr_r; n = logical
// output col; k = chunk-local invP(k_pos).
// ---------------------------------------------------------------------------
__global__ __launch_bounds__(256) void prologue(
    const float* __restrict__ Wl,    // L x 128 x 128
    const float* __restrict__ Wr,    // L x 896 x 128
    unsigned short* __restrict__ Bw16,// L x 8 x 128 x 128 bf16
    const float* __restrict__ x,     // N x 128
    unsigned short* __restrict__ hb, // N x 128 bf16 (position space)
    int* __restrict__ bcnt,
    float* __restrict__ gf)
{
    int t = blockIdx.x * 256 + threadIdx.x;
    if (t < NPK) {
        int k4 = t & 31;                // ushort4 index within 128-k row
        int n  = (t >> 5) & 127;        // logical output column
        int ch = (t >> 12) & 7;
        int l  = t >> 15;
        unsigned short o[4];
#pragma unroll
        for (int j = 0; j < 4; ++j) {
            int k_pos = k4 * 4 + j;
            int kp = k_pos & 63;
            int k = (k_pos & ~63) + (kp & 3) * 16 + (kp >> 2);   // chunk-local k
            float w = (ch == 0)
                ? Wl[(size_t)l * 16384 + k * 128 + n]
                : Wr[(size_t)l * 114688 + (size_t)((ch - 1) * 128 + k) * 128 + n];
            o[j] = f2bf(w);
        }
        ((ushort4*)Bw16)[t] = make_ushort4(o[0], o[1], o[2], o[3]);
    } else if (t < NPK + NCV) {
        int i = t - NPK;
        int row = i >> 5;
        int pg  = i & 31;               // positions pg*4 .. +3
        int span = pg >> 4;
        int q = pg & 15;
        const float* xr = x + (size_t)row * DD + span * 64 + q;
        ushort2 a = pk2bf(xr[0],  xr[16]);
        ushort2 b = pk2bf(xr[32], xr[48]);
        ((ushort4*)hb)[i] = make_ushort4(a.x, a.y, b.x, b.y);
    } else {
        int i = t - NPK - NCV;
        if (i < NB64 * 16) bcnt[i] = 0;
        else {
            i -= NB64 * 16;
            if (i < GG * DD) gf[i] = 0.f;
        }
    }
}

// ---------------------------------------------------------------------------
// Bucketed edge sort (2 passes). Buckets of 64 consecutive out-nodes.
// ---------------------------------------------------------------------------
__global__ __launch_bounds__(256) void bucket_hist(
    const int* __restrict__ node_out, int* __restrict__ bcnt, int E)
{
    int e = blockIdx.x * 256 + threadIdx.x;
    if (e < E) atomicAdd(&bcnt[(node_out[e] >> 6) * 16], 1);
}

__global__ __launch_bounds__(512) void bucket_scan(
    const int* __restrict__ bcnt, int* __restrict__ bstart,
    int* __restrict__ bcur, int nb)
{
    __shared__ int s[512];
    int t = threadIdx.x;
    int v = (t < nb) ? bcnt[t * 16] : 0;
    s[t] = v;
    __syncthreads();
#pragma unroll
    for (int off = 1; off < 512; off <<= 1) {
        int u = (t >= off) ? s[t - off] : 0;
        __syncthreads();
        s[t] += u;
        __syncthreads();
    }
    if (t <= nb) {
        int excl = s[t] - v;                 // for t==nb: v==0 -> total
        bstart[t] = excl;
        if (t < nb) bcur[t * 16] = excl;
    }
}

// pack.x = (out&63)<<18 | in<<3 | rel
__global__ __launch_bounds__(256) void bucket_scatter(
    const int* __restrict__ node_in,
    const int* __restrict__ node_out,
    const int* __restrict__ relation,
    const float* __restrict__ ew,
    int* __restrict__ bcur,
    int2* __restrict__ tmp,
    int E)
{
    int e = blockIdx.x * 256 + threadIdx.x;
    if (e >= E) return;
    int o = node_out[e];
    int pos = atomicAdd(&bcur[(o >> 6) * 16], 1);
    tmp[pos] = make_int2(((o & 63) << 18) | (node_in[e] << 3) | relation[e],
                         __float_as_int(ew[e]));
}

// One block per bucket: LDS counting sort over 64 local nodes; emits meta
// (x = (in<<8)|rel : in*256 = byte offset of bf16 h row, y = w) and start[].
__global__ __launch_bounds__(256) void bucket_sort(
    const int2* __restrict__ tmp,
    const int* __restrict__ bstart,
    int2* __restrict__ meta,
    int* __restrict__ start,
    int N)
{
    __shared__ int hist[64];
    __shared__ int scan[64];
    __shared__ int cur[64];
    const int b = blockIdx.x;
    const int t = threadIdx.x;
    const int s0 = bstart[b];
    const int s1 = bstart[b + 1];

    if (t < 64) hist[t] = 0;
    __syncthreads();
    for (int i = s0 + t; i < s1; i += 256)
        atomicAdd(&hist[((unsigned)tmp[i].x) >> 18], 1);
    __syncthreads();

    int v = (t < 64) ? hist[t] : 0;
    if (t < 64) scan[t] = v;
    __syncthreads();
#pragma unroll
    for (int off = 1; off < 64; off <<= 1) {
        int u = (t < 64 && t >= off) ? scan[t - off] : 0;
        __syncthreads();
        if (t < 64) scan[t] += u;
        __syncthreads();
    }
    if (t < 64) {
        int excl = scan[t] - v;
        cur[t] = s0 + excl;
        int node = b * 64 + t;
        if (node <= N) start[node] = s0 + excl;   // node==N -> start[N]=E
    }
    __syncthreads();

    for (int i = s0 + t; i < s1; i += 256) {
        int2 m = tmp[i];
        int j = ((unsigned)m.x) >> 18;
        int pos = atomicAdd(&cur[j], 1);
        int key = m.x & 0x3ffff;
        int in = key >> 3, rel = key & 7;
        meta[pos] = make_int2((in << 8) | rel, m.y);
    }
}

// ---------------------------------------------------------------------------
// aggregate_h: upd[n][r*128+p] = sum_{e:out=n,rel=r} w_e * h[in_e][p]  (fp8)
// One wave per node; 4 edges per step (group grp=lane>>4 owns edge e+grp);
// lane reads uint4 = 8 bf16 at positions l16*8..+7 (16 lanes x 16B = one
// 256-B h row; 7.68 MB source, ~L2-resident). Direct per-lane meta
// addressing (no cross-lane op in the address chain — round-7 lesson).
// Per-lane switch(rel) into statically-indexed acc[7][8]; partials reduced
// across the 4 groups with 2 shfl_xor; grp 0 writes the fp8 upd row.
// ---------------------------------------------------------------------------
__global__ __launch_bounds__(256) void aggregate_h(
    const unsigned short* __restrict__ hb,  // N x 128 bf16 (position space)
    const int* __restrict__ start,          // N+1
    const int2* __restrict__ meta,          // E: x=(in<<8)|rel, y=w bits
    unsigned char* __restrict__ upd,        // N x 896 fp8 (position space)
    int N)
{
    int wid = (blockIdx.x * 256 + threadIdx.x) >> 6;
    int lane = threadIdx.x & 63;
    if (wid >= N) return;

    const int grp  = lane >> 4;
    const int l16  = lane & 15;
    const int base = l16 * 16;         // BYTE offset into the 256-B row
    const char* hB = (const char*)hb;

    int e0 = start[wid];
    int e1 = start[wid + 1];

    float acc[7][8];
#pragma unroll
    for (int r = 0; r < 7; ++r)
#pragma unroll
        for (int j = 0; j < 8; ++j) acc[r][j] = 0.f;

#define FMA_CASE(R)                                     \
    acc[R][0] = fmaf(wt, d0, acc[R][0]);                \
    acc[R][1] = fmaf(wt, d1, acc[R][1]);                \
    acc[R][2] = fmaf(wt, d2, acc[R][2]);                \
    acc[R][3] = fmaf(wt, d3, acc[R][3]);                \
    acc[R][4] = fmaf(wt, d4, acc[R][4]);                \
    acc[R][5] = fmaf(wt, d5, acc[R][5]);                \
    acc[R][6] = fmaf(wt, d6, acc[R][6]);                \
    acc[R][7] = fmaf(wt, d7, acc[R][7]);

#define PROC_EDGE(m, u) do {                                            \
    float wt = __int_as_float((m).y);                                   \
    float d0 = __uint_as_float((u).x << 16);                            \
    float d1 = __uint_as_float((u).x & 0xffff0000u);                    \
    float d2 = __uint_as_float((u).y << 16);                            \
    float d3 = __uint_as_float((u).y & 0xffff0000u);                    \
    float d4 = __uint_as_float((u).z << 16);                            \
    float d5 = __uint_as_float((u).z & 0xffff0000u);                    \
    float d6 = __uint_as_float((u).w << 16);                            \
    float d7 = __uint_as_float((u).w & 0xffff0000u);                    \
    switch ((m).x & 7) {                                                \
        case 0: FMA_CASE(0) break;                                      \
        case 1: FMA_CASE(1) break;                                      \
        case 2: FMA_CASE(2) break;                                      \
        case 3: FMA_CASE(3) break;                                      \
        case 4: FMA_CASE(4) break;                                      \
        case 5: FMA_CASE(5) break;                                      \
        default: FMA_CASE(6) break;                                     \
    }                                                                   \
} while (0)

    int e = e0;
    for (; e + 8 <= e1; e += 8) {
        int2 m0 = meta[e + grp];
        int2 m1 = meta[e + 4 + grp];
        uint4 u0 = *(const uint4*)(hB + ((unsigned)m0.x & 0xffffff00u) + base);
        uint4 u1 = *(const uint4*)(hB + ((unsigned)m1.x & 0xffffff00u) + base);
        PROC_EDGE(m0, u0);
        PROC_EDGE(m1, u1);
    }
    for (; e + 4 <= e1; e += 4) {
        int2 m = meta[e + grp];
        uint4 u = *(const uint4*)(hB + ((unsigned)m.x & 0xffffff00u) + base);
        PROC_EDGE(m, u);
    }
    if (e + grp < e1) {                // predicated tail, <=3 edges
        int2 m = meta[e + grp];
        uint4 u = *(const uint4*)(hB + ((unsigned)m.x & 0xffffff00u) + base);
        PROC_EDGE(m, u);
    }
#undef PROC_EDGE
#undef FMA_CASE

    // reduce across the 4 groups (lanes with same l16)
#pragma unroll
    for (int r = 0; r < 7; ++r)
#pragma unroll
        for (int j = 0; j < 8; ++j) {
            acc[r][j] += __shfl_xor(acc[r][j], 16, 64);
            acc[r][j] += __shfl_xor(acc[r][j], 32, 64);
        }

    if (grp == 0) {
        unsigned char* dst = upd + (size_t)wid * 896 + l16 * 8;
#pragma unroll
        for (int r = 0; r < 7; ++r) {
            int lo = __builtin_amdgcn_cvt_pk_fp8_f32(acc[r][0], acc[r][1], 0, false);
            lo = __builtin_amdgcn_cvt_pk_fp8_f32(acc[r][2], acc[r][3], lo, true);
            int hi = __builtin_amdgcn_cvt_pk_fp8_f32(acc[r][4], acc[r][5], 0, false);
            hi = __builtin_amdgcn_cvt_pk_fp8_f32(acc[r][6], acc[r][7], hi, true);
            *(uint2*)(dst + r * 128) = make_uint2((unsigned)lo, (unsigned)hi);
        }
    }
}

// ---------------------------------------------------------------------------
// gemm_h: h_next = relu( [h | upd] (N x 1024) @ Bw16 (1024 x 128) + br+bl )
// All-bf16 MFMA. Block 64 rows x 128 cols, 4 waves (wave owns 64r x 32c,
// acc[4][2]); 8 K-chunks of 128. A chunk 0 = h via gl_lds (source-side
// swizzle); chunks 1-7 = upd fp8 -> reg-staged decode to bf16 -> swizzled
// ds_write (both-sides swizzle). B = 32 KB/chunk via gl_lds. LDS 48 KB.
// ---------------------------------------------------------------------------
__global__ __launch_bounds__(256) void gemm_h(
    const unsigned short* __restrict__ hb,   // N x 128 bf16 (position space)
    const unsigned char* __restrict__ upd,   // N x 896 fp8 (position space)
    const unsigned short* __restrict__ Bw16, // 8 x 128 x 128 bf16 (this layer)
    const float* __restrict__ br,            // 128 (logical)
    const float* __restrict__ bl,            // 128 (logical)
    unsigned short* __restrict__ hout,       // N x 128 bf16 or null
    float* __restrict__ nf,                  // N x 128 f32 (logical) or null
    int N)
{
    __shared__ unsigned short As[64 * 128];    // 16 KB
    __shared__ unsigned short Bs[128 * 128];   // 32 KB

    const int tid  = threadIdx.x;
    const int wave = tid >> 6;
    const int lane = tid & 63;
    const int quad = lane >> 4;
    const int l16  = lane & 15;
    const int row0 = blockIdx.x * 64;
    const int lr = lane >> 4;      // staging sub-row
    const int ls = lane & 15;      // staging 16B slot

    f32x4 acc[4][2];
#pragma unroll
    for (int mt = 0; mt < 4; ++mt)
#pragma unroll
        for (int nt = 0; nt < 2; ++nt)
            acc[mt][nt] = (f32x4){0.f, 0.f, 0.f, 0.f};

    const unsigned short* As_l = As + l16 * 128;
    const unsigned short* Bs_l = Bs + (wave * 32 + l16) * 128;
    const int swz = l16 & 7;

    for (int ch = 0; ch < 8; ++ch) {
        // ---- stage A (16 KB) ----
        if (ch == 0) {
#pragma unroll
            for (int i = 0; i < 4; ++i) {
                int g = i * 4 + wave;                // 0..15
                int r = g * 4 + lr;                  // 0..63
                int slot = ls ^ (r & 7);
                gl_lds16(hb + (size_t)(row0 + r) * 128 + slot * 8, As + g * 512);
            }
        } else {
            const unsigned char* usrc = upd + (size_t)row0 * 896 + (ch - 1) * 128;
#pragma unroll
            for (int i = 0; i < 4; ++i) {
                int sid = i * 256 + tid;             // 0..1023
                int r = sid >> 4, s = sid & 15;
                uint2 u = *(const uint2*)(usrc + (size_t)r * 896 + s * 8);
                f32x2 c0 = __builtin_amdgcn_cvt_pk_f32_fp8(u.x, false);
                f32x2 c1 = __builtin_amdgcn_cvt_pk_f32_fp8(u.x, true);
                f32x2 c2 = __builtin_amdgcn_cvt_pk_f32_fp8(u.y, false);
                f32x2 c3 = __builtin_amdgcn_cvt_pk_f32_fp8(u.y, true);
                ushort2 p0 = pk2bf(c0[0], c0[1]);
                ushort2 p1 = pk2bf(c1[0], c1[1]);
                ushort2 p2 = pk2bf(c2[0], c2[1]);
                ushort2 p3 = pk2bf(c3[0], c3[1]);
                uint4 o;
                o.x = (unsigned)p0.x | ((unsigned)p0.y << 16);
                o.y = (unsigned)p1.x | ((unsigned)p1.y << 16);
                o.z = (unsigned)p2.x | ((unsigned)p2.y << 16);
                o.w = (unsigned)p3.x | ((unsigned)p3.y << 16);
                ((uint4*)As)[r * 16 + (s ^ (r & 7))] = o;
            }
        }
        // ---- stage B (32 KB = 32 issues, 8/wave) ----
        const unsigned short* Bsrc = Bw16 + (size_t)ch * 16384;
#pragma unroll
        for (int i = 0; i < 8; ++i) {
            int g = i * 4 + wave;                    // 0..31
            int r = g * 4 + lr;                      // 0..127
            int slot = ls ^ (r & 7);
            gl_lds16(Bsrc + (size_t)r * 128 + slot * 8, Bs + g * 512);
        }
        __syncthreads();

        // ---- compute chunk: 32 MFMA / wave ----
#pragma unroll
        for (int kc = 0; kc < 4; ++kc) {
            int so = ((kc * 4 + quad) ^ swz) * 8;    // swizzled ushort offset
            bf16x8 b0 = *(const bf16x8*)(Bs_l + so);
            bf16x8 b1 = *(const bf16x8*)(Bs_l + 16 * 128 + so);
#pragma unroll
            for (int mt = 0; mt < 4; ++mt) {
                bf16x8 a = *(const bf16x8*)(As_l + mt * 16 * 128 + so);
                acc[mt][0] = __builtin_amdgcn_mfma_f32_16x16x32_bf16(a, b0, acc[mt][0], 0, 0, 0);
                acc[mt][1] = __builtin_amdgcn_mfma_f32_16x16x32_bf16(a, b1, acc[mt][1], 0, 0, 0);
            }
        }
        __syncthreads();
    }

    // ---- epilogue: bias + relu ----
    const int c0 = wave * 32 + l16;          // logical col (nt=0); nt=1: +16
    const float bias0 = br[c0] + bl[c0];
    const float bias1 = br[c0 + 16] + bl[c0 + 16];
    // position of (nt) value: (wave>>1)*64 + l16*4 + (wave&1)*2 + nt
    const int pbase = (wave >> 1) * 64 + l16 * 4 + (wave & 1) * 2;
#pragma unroll
    for (int mt = 0; mt < 4; ++mt) {
#pragma unroll
        for (int reg = 0; reg < 4; ++reg) {
            int row = row0 + mt * 16 + quad * 4 + reg;
            if (row < N) {
                float v0 = fmaxf(acc[mt][0][reg] + bias0, 0.f);
                float v1 = fmaxf(acc[mt][1][reg] + bias1, 0.f);
                if (hout) {
                    ushort2 p = pk2bf(v0, v1);
                    *(ushort2*)(hout + (size_t)row * 128 + pbase) = p;
                }
                if (nf) {
                    nf[(size_t)row * DD + c0]      = v0;
                    nf[(size_t)row * DD + c0 + 16] = v1;
                }
            }
        }
    }
}

// ---------------------------------------------------------------------------
// Graph segment sum: gf[n2g[n]] += nf[n] (n2g sorted).
// ---------------------------------------------------------------------------
__global__ __launch_bounds__(256) void graph_sum(
    const float* __restrict__ nf,
    const int* __restrict__ n2g,
    float* __restrict__ gf,
    int N)
{
    int t = blockIdx.x * 256 + threadIdx.x;
    int chunk = t >> 5;
    int lane = t & 31;
    int n0 = chunk * 16;
    if (n0 >= N) return;
    int nend = n0 + 16; if (nend > N) nend = N;

    float4 acc = make_float4(0.f, 0.f, 0.f, 0.f);
    int curg = n2g[n0];
    for (int n = n0; n < nend; ++n) {
        int g = n2g[n];
        if (g != curg) {
            float* dst = gf + (size_t)curg * DD + lane * 4;
            atomicAdd(dst + 0, acc.x); atomicAdd(dst + 1, acc.y);
            atomicAdd(dst + 2, acc.z); atomicAdd(dst + 3, acc.w);
            acc = make_float4(0.f, 0.f, 0.f, 0.f);
            curg = g;
        }
        float4 v = *(const float4*)(nf + (size_t)n * DD + lane * 4);
        acc.x += v.x; acc.y += v.y; acc.z += v.z; acc.w += v.w;
    }
    float* dst = gf + (size_t)curg * DD + lane * 4;
    atomicAdd(dst + 0, acc.x); atomicAdd(dst + 1, acc.y);
    atomicAdd(dst + 2, acc.z); atomicAdd(dst + 3, acc.w);
}

// ---------------------------------------------------------------------------
extern "C" void kernel_launch(void* const* d_in, const int* in_sizes, int n_in,
                              void* d_out, int out_size, void* d_ws, size_t ws_size,
                              hipStream_t stream)
{
    const float* x        = (const float*)d_in[0];
    const int*   node_in  = (const int*)d_in[1];
    const int*   node_out = (const int*)d_in[2];
    const int*   relation = (const int*)d_in[3];
    const float* ew       = (const float*)d_in[4];
    const int*   n2g      = (const int*)d_in[5];
    const float* Wr       = (const float*)d_in[6];
    const float* br       = (const float*)d_in[7];
    const float* Wl       = (const float*)d_in[8];
    const float* bl       = (const float*)d_in[9];

    float* out = (float*)d_out;
    float* gf = out;                 // 16 x 128
    float* nf = out + GG * DD;       // 30000 x 128

    // Workspace (~53 MB). GEMM A-staging reads up to 16 rows past N:
    // upd overruns into hbA, hbA into hbB, hbB into Bw16 (reads only;
    // all outputs row-masked).
    char* w = (char*)d_ws;
    unsigned char*  upd  = (unsigned char*)w;  w += (size_t)NN * RR * DD;        // 26.88 MB
    unsigned short* hbA  = (unsigned short*)w; w += (size_t)NN * DD * 2;         // 7.68 MB
    unsigned short* hbB  = (unsigned short*)w; w += (size_t)NN * DD * 2;         // 7.68 MB
    unsigned short* Bw16 = (unsigned short*)w; w += (size_t)LL * 8 * 128 * 128 * 2; // 0.79 MB
    int2*  meta   = (int2*)w;                  w += (size_t)NE * 8;              // 4.8 MB
    int2*  tmp    = (int2*)w;                  w += (size_t)NE * 8;              // 4.8 MB
    int*   start  = (int*)w;                   w += (size_t)(NN + 1) * 4 + 60;
    int*   bcnt   = (int*)w;                   w += (size_t)NB64 * 16 * 4 + 64;
    int*   bcur   = (int*)w;                   w += (size_t)NB64 * 16 * 4 + 64;
    int*   bstart = (int*)w;                   w += (size_t)(NB64 + 1) * 4 + 60;

    const int N = NN, E = NE;

    // ---- fused prologue + bucketed edge sort ----
    int ptot = NPK + NCV + NB64 * 16 + GG * DD;
    prologue<<<(ptot + 255) / 256, 256, 0, stream>>>(
        Wl, Wr, Bw16, x, hbA, bcnt, gf);

    bucket_hist<<<(E + 255) / 256, 256, 0, stream>>>(node_out, bcnt, E);
    bucket_scan<<<1, 512, 0, stream>>>(bcnt, bstart, bcur, NB64);
    bucket_scatter<<<(E + 255) / 256, 256, 0, stream>>>(
        node_in, node_out, relation, ew, bcur, tmp, E);
    bucket_sort<<<NB64, 256, 0, stream>>>(tmp, bstart, meta, start, N);

    // ---- layers: h-space aggregate (L2-friendly gather) + bf16 K=1024 GEMM -
    unsigned short* hin = hbA;
    unsigned short* hnext = hbB;
    for (int l = 0; l < LL; ++l) {
        const float* br_l = br + (size_t)l * DD;
        const float* bl_l = bl + (size_t)l * DD;
        const unsigned short* Bw_l = Bw16 + (size_t)l * 8 * 128 * 128;
        bool last = (l == LL - 1);

        aggregate_h<<<(N * 64 + 255) / 256, 256, 0, stream>>>(
            hin, start, meta, upd, N);

        gemm_h<<<(N + 63) / 64, 256, 0, stream>>>(
            hin, upd, Bw_l, br_l, bl_l,
            last ? (unsigned short*)nullptr : hnext,
            last ? nf : (float*)nullptr, N);

        unsigned short* t = hin; hin = hnext; hnext = t;
    }

    // ---- graph_feature ----
    int chunks = (N + 15) / 16;
    graph_sum<<<(chunks * 32 + 255) / 256, 256, 0, stream>>>(nf, n2g, gf, N);
}

// Round 10
// 293.145 us; speedup vs baseline: 1.3088x; 1.3088x over previous
//
#include <hip/hip_runtime.h>
#include <hip/hip_bf16.h>

// Problem constants (match reference setup_inputs)
#define NN 30000      // nodes
#define NE 600000     // edges
#define DD 128        // feature dim
#define RR 7          // relations
#define GG 16         // graphs
#define LL 3          // layers

#define NB64 ((NN + 63) / 64)   // 469 buckets of 64 nodes
#define NPACK (LL * 1024 * DD)  // weight-pack elements
#define NCVT  (NN * 32)         // x-convert work items (4 cols each)

typedef short bf16x8 __attribute__((ext_vector_type(8)));  // 8 bf16 = 4 VGPRs
typedef float f32x4  __attribute__((ext_vector_type(4)));
typedef float f32x2  __attribute__((ext_vector_type(2)));

// Feature-position permutation (per 64-col span): pos = (c&15)*4 + (c>>4),
// inverse c = (p&3)*16 + (p>>2). h buffers / haccb / Z live in position
// space. The GEMM epilogue's store pattern REALIZES the permutation, so
// packed weights are indexed by LOGICAL output column; only the k dim of
// Bw is position-permuted. nf (f32 output) un-permutes at write.

// ---- bf16 helpers ----------------------------------------------------------
__device__ __forceinline__ unsigned short f2bf(float f) {
    unsigned u = __float_as_uint(f);
    unsigned r = (u + 0x7fffu + ((u >> 16) & 1u)) >> 16;   // round-nearest-even
    return (unsigned short)r;
}
__device__ __forceinline__ float bf2f(unsigned short b) {
    return __uint_as_float(((unsigned)b) << 16);
}
__device__ __forceinline__ ushort2 pk2bf(float a, float b) {
    __hip_bfloat162 t = __float22bfloat162_rn(make_float2(a, b));
    return *(ushort2*)&t;
}

// async global->LDS, 16B per lane; LDS dest = wave-uniform base + lane*16
__device__ __forceinline__ void gl_lds16(const void* g, void* l) {
    __builtin_amdgcn_global_load_lds(
        (const __attribute__((address_space(1))) void*)g,
        (__attribute__((address_space(3))) void*)l, 16, 0, 0);
}

// ---------------------------------------------------------------------------
// Fused prologue: weight pack + x->bf16 convert + bcnt/gf zero (one dispatch).
// Bw[l][n][k_pos]: n = LOGICAL output column (0..127 Wl col, 128+q -> Wr);
// k = invP(k_pos) position-permuted.
// ---------------------------------------------------------------------------
__global__ __launch_bounds__(256) void pack_and_convert(
    const float* __restrict__ Wl,   // L x 128 x 128
    const float* __restrict__ Wr,   // L x 896 x 128
    unsigned short* __restrict__ Bw,// L x 1024 x 128
    const float* __restrict__ x,    // N x 128
    unsigned short* __restrict__ hb,// N x 128 (position space)
    int* __restrict__ bcnt,
    float* __restrict__ gf)
{
    int t = blockIdx.x * 256 + threadIdx.x;
    if (t < NPACK) {
        int l = t >> 17;
        int rem = t & 131071;
        int n = rem >> 7;              // logical output column / z-index
        int k_pos = rem & 127;
        int kp = k_pos & 63;
        int k = (k_pos & ~63) + (kp & 3) * 16 + (kp >> 2);   // logical k
        float v;
        if (n < DD) {
            v = Wl[(size_t)l * DD * DD + k * DD + n];
        } else {
            int q = n - DD;
            v = Wr[(size_t)l * RR * DD * DD + (size_t)((q >> 7) * DD + k) * DD + (q & 127)];
        }
        Bw[t] = f2bf(v);
    } else if (t < NPACK + NCVT) {
        int i = t - NPACK;
        int row = i >> 5;
        int pg  = i & 31;              // position group: positions pg*4..+3
        int span = pg >> 4;
        int q = pg & 15;
        const float* xr = x + (size_t)row * DD + span * 64 + q;
        ushort2 a = pk2bf(xr[0],  xr[16]);
        ushort2 b = pk2bf(xr[32], xr[48]);
        ((ushort4*)hb)[i] = make_ushort4(a.x, a.y, b.x, b.y);
    } else {
        int i = t - NPACK - NCVT;
        if (i < NB64 * 16) bcnt[i] = 0;
        else {
            i -= NB64 * 16;
            if (i < GG * DD) gf[i] = 0.f;
        }
    }
}

// ---------------------------------------------------------------------------
// Bucketed edge sort (2 passes). Buckets of 64 consecutive out-nodes.
// ---------------------------------------------------------------------------
__global__ __launch_bounds__(256) void bucket_hist(
    const int* __restrict__ node_out, int* __restrict__ bcnt, int E)
{
    int e = blockIdx.x * 256 + threadIdx.x;
    if (e < E) atomicAdd(&bcnt[(node_out[e] >> 6) * 16], 1);
}

__global__ __launch_bounds__(512) void bucket_scan(
    const int* __restrict__ bcnt, int* __restrict__ bstart,
    int* __restrict__ bcur, int nb)
{
    __shared__ int s[512];
    int t = threadIdx.x;
    int v = (t < nb) ? bcnt[t * 16] : 0;
    s[t] = v;
    __syncthreads();
#pragma unroll
    for (int off = 1; off < 512; off <<= 1) {
        int u = (t >= off) ? s[t - off] : 0;
        __syncthreads();
        s[t] += u;
        __syncthreads();
    }
    if (t <= nb) {
        int excl = s[t] - v;                 // for t==nb: v==0 -> total
        bstart[t] = excl;
        if (t < nb) bcur[t * 16] = excl;
    }
}

// pack.x = (out&63)<<18 | in<<3 | rel
__global__ __launch_bounds__(256) void bucket_scatter(
    const int* __restrict__ node_in,
    const int* __restrict__ node_out,
    const int* __restrict__ relation,
    const float* __restrict__ ew,
    int* __restrict__ bcur,
    int2* __restrict__ tmp,
    int E)
{
    int e = blockIdx.x * 256 + threadIdx.x;
    if (e >= E) return;
    int o = node_out[e];
    int pos = atomicAdd(&bcur[(o >> 6) * 16], 1);
    tmp[pos] = make_int2(((o & 63) << 18) | (node_in[e] << 3) | relation[e],
                         __float_as_int(ew[e]));
}

// One block per bucket: LDS counting sort over 64 local nodes; emits meta
// (zoff = (in*7+rel)*128 BYTE offset into fp8 Z, w) and start[] array.
__global__ __launch_bounds__(256) void bucket_sort(
    const int2* __restrict__ tmp,
    const int* __restrict__ bstart,
    int2* __restrict__ meta,
    int* __restrict__ start,
    int N)
{
    __shared__ int hist[64];
    __shared__ int scan[64];
    __shared__ int cur[64];
    const int b = blockIdx.x;
    const int t = threadIdx.x;
    const int s0 = bstart[b];
    const int s1 = bstart[b + 1];

    if (t < 64) hist[t] = 0;
    __syncthreads();
    for (int i = s0 + t; i < s1; i += 256)
        atomicAdd(&hist[((unsigned)tmp[i].x) >> 18], 1);
    __syncthreads();

    int v = (t < 64) ? hist[t] : 0;
    if (t < 64) scan[t] = v;
    __syncthreads();
#pragma unroll
    for (int off = 1; off < 64; off <<= 1) {
        int u = (t < 64 && t >= off) ? scan[t - off] : 0;
        __syncthreads();
        if (t < 64) scan[t] += u;
        __syncthreads();
    }
    if (t < 64) {
        int excl = scan[t] - v;
        cur[t] = s0 + excl;
        int node = b * 64 + t;
        if (node <= N) start[node] = s0 + excl;   // node==N -> start[N]=E
    }
    __syncthreads();

    for (int i = s0 + t; i < s1; i += 256) {
        int2 m = tmp[i];
        int j = ((unsigned)m.x) >> 18;
        int pos = atomicAdd(&cur[j], 1);
        int key = m.x & 0x3ffff;
        int in = key >> 3, rel = key & 7;
        meta[pos] = make_int2((in * RR + rel) << 7, m.y);   // byte offset (fp8)
    }
}

// ---------------------------------------------------------------------------
// MFMA GEMM (internal column-loop): [haccb | Zb8] (N x 1024) = hb @ Bw.
// One block per 64-row tile (grid 469, 1-D). A (16 KB) staged ONCE; the 8
// output chunks of 128 cols loop internally, each re-staging Bs (32 KB) from
// the L2-hot weight buffer. Wave owns 16 rows x 128 chunk-cols, acc[8].
// Per-chunk epilogue: chunk 0 -> haccb (bias, bf16 ushort4 x2); chunks 1-7
// -> Z row (ch-1), two dwords of 4 fp8. Store pattern realizes the position
// permutation: p = (nt>>2)*64 + l16*4 + (nt&3). LDS 48 KB -> 3 blocks/CU.
// ---------------------------------------------------------------------------
__global__ __launch_bounds__(256) void gemm_mfma(
    const unsigned short* __restrict__ hb,   // N x 128 bf16 (position space)
    const unsigned short* __restrict__ Bw,   // 1024 x 128 bf16 (n-major)
    const float* __restrict__ br,            // 128 (logical)
    const float* __restrict__ bl,            // 128 (logical)
    unsigned short* __restrict__ haccb,      // N x 128 bf16 (position space)
    unsigned char* __restrict__ Zb8,         // N x 896 fp8 (position space)
    int N)
{
    __shared__ unsigned short As[64 * 128];    // 16 KB
    __shared__ unsigned short Bs[128 * 128];   // 32 KB

    const int tid  = threadIdx.x;
    const int wave = tid >> 6;
    const int lane = tid & 63;
    const int quad = lane >> 4;
    const int l16  = lane & 15;
    const int row0 = blockIdx.x * 64;

    const int lr = lane >> 4;      // sub-row within a 4-row staging group
    const int ls = lane & 15;      // 16B slot within a 256B row

    // ---- stage A once: 16 groups x 4 rows, swizzled source ----
#pragma unroll
    for (int i = 0; i < 4; ++i) {
        int g = i * 4 + wave;                // 0..15
        int r = g * 4 + lr;                  // 0..63
        int slot = ls ^ (r & 7);
        gl_lds16(hb + (size_t)(row0 + r) * 128 + slot * 8, As + g * 512);
    }
    // ---- stage B chunk 0: 32 groups x 4 rows, swizzled source ----
#pragma unroll
    for (int i = 0; i < 8; ++i) {
        int g = i * 4 + wave;                // 0..31
        int r = g * 4 + lr;                  // 0..127
        int slot = ls ^ (r & 7);
        gl_lds16(Bw + (size_t)r * 128 + slot * 8, Bs + g * 512);
    }

    const unsigned short* As_w = As + (wave * 16 + l16) * 128;
    const unsigned short* Bs_l = Bs + l16 * 128;
    const int swz = l16 & 7;

    for (int ch = 0; ch < 8; ++ch) {
        if (ch > 0) {
            __syncthreads();   // previous chunk's ds_reads complete
            const unsigned short* Bsrc = Bw + (size_t)ch * 16384;
#pragma unroll
            for (int i = 0; i < 8; ++i) {
                int g = i * 4 + wave;
                int r = g * 4 + lr;
                int slot = ls ^ (r & 7);
                gl_lds16(Bsrc + (size_t)r * 128 + slot * 8, Bs + g * 512);
            }
        }
        __syncthreads();       // staging complete (barrier drains vmcnt)

        f32x4 acc[8];
#pragma unroll
        for (int nt = 0; nt < 8; ++nt) acc[nt] = (f32x4){0.f, 0.f, 0.f, 0.f};

#pragma unroll
        for (int kc = 0; kc < 4; ++kc) {
            int so = ((kc * 4 + quad) ^ swz) * 8;   // swizzled ushort offset
            bf16x8 a = *(const bf16x8*)(As_w + so);
#pragma unroll
            for (int nt = 0; nt < 8; ++nt) {
                bf16x8 b = *(const bf16x8*)(Bs_l + nt * 16 * 128 + so);
                acc[nt] = __builtin_amdgcn_mfma_f32_16x16x32_bf16(a, b, acc[nt], 0, 0, 0);
            }
        }

        // ---- per-chunk epilogue ----
        if (ch == 0) {
            float bias[8];
#pragma unroll
            for (int nt = 0; nt < 8; ++nt) {
                int c = nt * 16 + l16;
                bias[nt] = br[c] + bl[c];
            }
#pragma unroll
            for (int reg = 0; reg < 4; ++reg) {
                int row = row0 + wave * 16 + quad * 4 + reg;
                if (row < N) {
                    ushort2 p01 = pk2bf(acc[0][reg] + bias[0], acc[1][reg] + bias[1]);
                    ushort2 p23 = pk2bf(acc[2][reg] + bias[2], acc[3][reg] + bias[3]);
                    ushort2 p45 = pk2bf(acc[4][reg] + bias[4], acc[5][reg] + bias[5]);
                    ushort2 p67 = pk2bf(acc[6][reg] + bias[6], acc[7][reg] + bias[7]);
                    unsigned short* dst = haccb + (size_t)row * 128 + l16 * 4;
                    *(ushort4*)(dst)      = make_ushort4(p01.x, p01.y, p23.x, p23.y);
                    *(ushort4*)(dst + 64) = make_ushort4(p45.x, p45.y, p67.x, p67.y);
                }
            }
        } else {
#pragma unroll
            for (int reg = 0; reg < 4; ++reg) {
                int row = row0 + wave * 16 + quad * 4 + reg;
                if (row < N) {
                    int u0 = __builtin_amdgcn_cvt_pk_fp8_f32(acc[0][reg], acc[1][reg], 0, false);
                    u0 = __builtin_amdgcn_cvt_pk_fp8_f32(acc[2][reg], acc[3][reg], u0, true);
                    int u1 = __builtin_amdgcn_cvt_pk_fp8_f32(acc[4][reg], acc[5][reg], 0, false);
                    u1 = __builtin_amdgcn_cvt_pk_fp8_f32(acc[6][reg], acc[7][reg], u1, true);
                    unsigned char* dst = Zb8 + (size_t)row * (RR * DD) + (ch - 1) * 128 + l16 * 4;
                    *(int*)(dst)      = u0;
                    *(int*)(dst + 64) = u1;
                }
            }
        }
    }
}

// ---------------------------------------------------------------------------
// Aggregate (fp8, direct-addressed wide gather):
//   o[n] = relu(haccb[n] + sum_e w_e * Z8[zoff_e])
// One wave per node. 4 edges per gather instruction: group grp=lane>>4 owns
// edge e+grp; lane reads uint2 (8 fp8) at positions l16*8..+7 — 16 lanes x
// 8 B = exactly one 128-B row. Meta read DIRECTLY per lane (no cross-lane op
// in the address chain — round-7 lesson). Main loop x8 = 2 gather chains.
// ---------------------------------------------------------------------------
__global__ __launch_bounds__(256) void aggregate(
    const unsigned char* __restrict__ Zb8,  // N x 896 fp8
    const int* __restrict__ start,          // N+1
    const int2* __restrict__ meta,          // E: x=(in*7+rel)*128 byte offset
    const unsigned short* __restrict__ haccb, // N x 128 bf16 (position space)
    float* __restrict__ out_f32,            // N x 128 (logical) or null
    unsigned short* __restrict__ out_bf16,  // N x 128 (position space) or null
    int N)
{
    int wid = (blockIdx.x * 256 + threadIdx.x) >> 6;
    int lane = threadIdx.x & 63;
    if (wid >= N) return;

    const int grp  = lane >> 4;        // 0..3: edge slot within 4-edge group
    const int l16  = lane & 15;
    const int base = l16 * 8;          // first of this lane's 8 positions

    int e0 = start[wid];
    int e1 = start[wid + 1];

    float acc[8];
#pragma unroll
    for (int k = 0; k < 8; ++k) acc[k] = 0.f;

#define FMA8(u, wt) do {                                                \
    f32x2 d0 = __builtin_amdgcn_cvt_pk_f32_fp8((u).x, false);           \
    f32x2 d1 = __builtin_amdgcn_cvt_pk_f32_fp8((u).x, true);            \
    f32x2 d2 = __builtin_amdgcn_cvt_pk_f32_fp8((u).y, false);           \
    f32x2 d3 = __builtin_amdgcn_cvt_pk_f32_fp8((u).y, true);            \
    acc[0] = fmaf((wt), d0[0], acc[0]);                                 \
    acc[1] = fmaf((wt), d0[1], acc[1]);                                 \
    acc[2] = fmaf((wt), d1[0], acc[2]);                                 \
    acc[3] = fmaf((wt), d1[1], acc[3]);                                 \
    acc[4] = fmaf((wt), d2[0], acc[4]);                                 \
    acc[5] = fmaf((wt), d2[1], acc[5]);                                 \
    acc[6] = fmaf((wt), d3[0], acc[6]);                                 \
    acc[7] = fmaf((wt), d3[1], acc[7]);                                 \
} while (0)

    int e = e0;
    for (; e + 8 <= e1; e += 8) {
        int2 m0 = meta[e + grp];
        int2 m1 = meta[e + 4 + grp];
        uint2 u0 = *(const uint2*)(Zb8 + (size_t)(unsigned)m0.x + base);
        uint2 u1 = *(const uint2*)(Zb8 + (size_t)(unsigned)m1.x + base);
        float w0 = __int_as_float(m0.y);
        float w1 = __int_as_float(m1.y);
        FMA8(u0, w0);
        FMA8(u1, w1);
    }
    for (; e + 4 <= e1; e += 4) {
        int2 m = meta[e + grp];
        uint2 u = *(const uint2*)(Zb8 + (size_t)(unsigned)m.x + base);
        float wt = __int_as_float(m.y);
        FMA8(u, wt);
    }
    if (e + grp < e1) {                // predicated tail, <=3 edges
        int2 m = meta[e + grp];
        uint2 u = *(const uint2*)(Zb8 + (size_t)(unsigned)m.x + base);
        float wt = __int_as_float(m.y);
        FMA8(u, wt);
    }
#undef FMA8

    // reduce the 4 per-group partials (lanes with same l16)
#pragma unroll
    for (int k = 0; k < 8; ++k) {
        acc[k] += __shfl_xor(acc[k], 16, 64);
        acc[k] += __shfl_xor(acc[k], 32, 64);
    }

    // haccb (includes br+bl), position space
    uint4 hb4 = *(const uint4*)(haccb + (size_t)wid * DD + base);
    float o[8];
    o[0] = fmaxf(__uint_as_float(hb4.x << 16)         + acc[0], 0.f);
    o[1] = fmaxf(__uint_as_float(hb4.x & 0xffff0000u) + acc[1], 0.f);
    o[2] = fmaxf(__uint_as_float(hb4.y << 16)         + acc[2], 0.f);
    o[3] = fmaxf(__uint_as_float(hb4.y & 0xffff0000u) + acc[3], 0.f);
    o[4] = fmaxf(__uint_as_float(hb4.z << 16)         + acc[4], 0.f);
    o[5] = fmaxf(__uint_as_float(hb4.z & 0xffff0000u) + acc[5], 0.f);
    o[6] = fmaxf(__uint_as_float(hb4.w << 16)         + acc[6], 0.f);
    o[7] = fmaxf(__uint_as_float(hb4.w & 0xffff0000u) + acc[7], 0.f);

    if (grp == 0) {
        if (out_bf16) {   // h_next stays in position space -> contiguous
            ushort2 p0 = pk2bf(o[0], o[1]);
            ushort2 p1 = pk2bf(o[2], o[3]);
            ushort2 p2 = pk2bf(o[4], o[5]);
            ushort2 p3 = pk2bf(o[6], o[7]);
            uint4 ub;
            ub.x = (unsigned)p0.x | ((unsigned)p0.y << 16);
            ub.y = (unsigned)p1.x | ((unsigned)p1.y << 16);
            ub.z = (unsigned)p2.x | ((unsigned)p2.y << 16);
            ub.w = (unsigned)p3.x | ((unsigned)p3.y << 16);
            *(uint4*)(out_bf16 + (size_t)wid * DD + base) = ub;
        }
        if (out_f32) {    // nf is logical order: un-permute
            // position p = l16*8+j -> col = (l16>>3)*64 + (j&3)*16 + (l16&7)*2 + (j>>2)
            int cb = ((l16 >> 3) << 6) + ((l16 & 7) << 1);
            float* dst = out_f32 + (size_t)wid * DD;
#pragma unroll
            for (int j = 0; j < 4; ++j) {
                *(float2*)(dst + cb + j * 16) = make_float2(o[j], o[j + 4]);
            }
        }
    }
}

// ---------------------------------------------------------------------------
// Graph segment sum: gf[n2g[n]] += nf[n] (n2g sorted).
// ---------------------------------------------------------------------------
__global__ __launch_bounds__(256) void graph_sum(
    const float* __restrict__ nf,
    const int* __restrict__ n2g,
    float* __restrict__ gf,
    int N)
{
    int t = blockIdx.x * 256 + threadIdx.x;
    int chunk = t >> 5;
    int lane = t & 31;
    int n0 = chunk * 16;
    if (n0 >= N) return;
    int nend = n0 + 16; if (nend > N) nend = N;

    float4 acc = make_float4(0.f, 0.f, 0.f, 0.f);
    int curg = n2g[n0];
    for (int n = n0; n < nend; ++n) {
        int g = n2g[n];
        if (g != curg) {
            float* dst = gf + (size_t)curg * DD + lane * 4;
            atomicAdd(dst + 0, acc.x); atomicAdd(dst + 1, acc.y);
            atomicAdd(dst + 2, acc.z); atomicAdd(dst + 3, acc.w);
            acc = make_float4(0.f, 0.f, 0.f, 0.f);
            curg = g;
        }
        float4 v = *(const float4*)(nf + (size_t)n * DD + lane * 4);
        acc.x += v.x; acc.y += v.y; acc.z += v.z; acc.w += v.w;
    }
    float* dst = gf + (size_t)curg * DD + lane * 4;
    atomicAdd(dst + 0, acc.x); atomicAdd(dst + 1, acc.y);
    atomicAdd(dst + 2, acc.z); atomicAdd(dst + 3, acc.w);
}

// ---------------------------------------------------------------------------
extern "C" void kernel_launch(void* const* d_in, const int* in_sizes, int n_in,
                              void* d_out, int out_size, void* d_ws, size_t ws_size,
                              hipStream_t stream)
{
    const float* x        = (const float*)d_in[0];
    const int*   node_in  = (const int*)d_in[1];
    const int*   node_out = (const int*)d_in[2];
    const int*   relation = (const int*)d_in[3];
    const float* ew       = (const float*)d_in[4];
    const int*   n2g      = (const int*)d_in[5];
    const float* Wr       = (const float*)d_in[6];
    const float* br       = (const float*)d_in[7];
    const float* Wl       = (const float*)d_in[8];
    const float* bl       = (const float*)d_in[9];

    float* out = (float*)d_out;
    float* gf = out;                 // 16 x 128
    float* nf = out + GG * DD;       // 30000 x 128

    // Workspace (~62 MB). GEMM A-staging overruns by up to 16 rows past N;
    // hbA overruns into hbB, hbB into Bw (reads only, outputs row-masked).
    char* w = (char*)d_ws;
    unsigned char*  Zb8  = (unsigned char*)w;  w += (size_t)NN * RR * DD;       // 26.88 MB
    unsigned short* haccb= (unsigned short*)w; w += (size_t)NN * DD * 2;        // 7.68 MB
    unsigned short* hbA  = (unsigned short*)w; w += (size_t)NN * DD * 2;        // 7.68 MB
    unsigned short* hbB  = (unsigned short*)w; w += (size_t)NN * DD * 2;        // 7.68 MB
    unsigned short* Bw   = (unsigned short*)w; w += (size_t)LL * 1024 * DD * 2; // 0.79 MB
    int2*  meta   = (int2*)w;                  w += (size_t)NE * 8;             // 4.8 MB
    int2*  tmp    = (int2*)w;                  w += (size_t)NE * 8;             // 4.8 MB
    int*   start  = (int*)w;                   w += (size_t)(NN + 1) * 4 + 60;
    int*   bcnt   = (int*)w;                   w += (size_t)NB64 * 16 * 4 + 64;
    int*   bcur   = (int*)w;                   w += (size_t)NB64 * 16 * 4 + 64;
    int*   bstart = (int*)w;                   w += (size_t)(NB64 + 1) * 4 + 60;

    const int N = NN, E = NE;

    // ---- fused prologue + bucketed edge sort ----
    int ptot = NPACK + NCVT + NB64 * 16 + GG * DD;
    pack_and_convert<<<(ptot + 255) / 256, 256, 0, stream>>>(
        Wl, Wr, Bw, x, hbA, bcnt, gf);

    bucket_hist<<<(E + 255) / 256, 256, 0, stream>>>(node_out, bcnt, E);
    bucket_scan<<<1, 512, 0, stream>>>(bcnt, bstart, bcur, NB64);
    bucket_scatter<<<(E + 255) / 256, 256, 0, stream>>>(
        node_in, node_out, relation, ew, bcur, tmp, E);
    bucket_sort<<<NB64, 256, 0, stream>>>(tmp, bstart, meta, start, N);

    // ---- layers ----
    unsigned short* hin = hbA;
    unsigned short* hnext = hbB;
    for (int l = 0; l < LL; ++l) {
        const float* br_l = br + (size_t)l * DD;
        const float* bl_l = bl + (size_t)l * DD;
        const unsigned short* Bw_l = Bw + (size_t)l * 1024 * DD;

        gemm_mfma<<<(N + 63) / 64, 256, 0, stream>>>(
            hin, Bw_l, br_l, bl_l, haccb, Zb8, N);

        bool last = (l == LL - 1);
        aggregate<<<(N * 64 + 255) / 256, 256, 0, stream>>>(
            Zb8, start, meta, haccb,
            last ? nf : (float*)nullptr,
            last ? (unsigned short*)nullptr : hnext, N);

        unsigned short* t = hin; hin = hnext; hnext = t;
    }

    // ---- graph_feature ----
    int chunks = (N + 15) / 16;
    graph_sum<<<(chunks * 32 + 255) / 256, 256, 0, stream>>>(nf, n2g, gf, N);
}